// Round 20
// baseline (210.026 us; speedup 1.0000x reference)
//
#include <hip/hip_runtime.h>
#include <hip/hip_bf16.h>

#define SCOPE 63
#define BT 256
#define RPB 128   // rows per block

typedef __attribute__((ext_vector_type(8))) __bf16 v8bf;
typedef __attribute__((ext_vector_type(4))) float f32x4;

__device__ __forceinline__ float4 ld4u(const float* p) {
    float4 v; __builtin_memcpy(&v, p, 16); return v;
}
__device__ __forceinline__ void st4u(float* p, float4 v) {
    __builtin_memcpy(p, &v, 16);
}

// ---------------------------------------------------------------------------
// Kernel 1: inverse filter g = IFFT( 1 / FFT(delta - f) ) in fp64. Negligible.
// ---------------------------------------------------------------------------
__global__ void compute_inverse_filter(const float* __restrict__ f,
                                       float* __restrict__ g) {
    __shared__ double hre[SCOPE];
    __shared__ double him[SCOPE];
    const double TWO_PI = 6.283185307179586476925286766559;
    int t = threadIdx.x;
    if (t < SCOPE) {
        double re = 0.0, im = 0.0;
        for (int n = 0; n < SCOPE; ++n) {
            double x = (n == 0 ? 1.0 : 0.0) - (double)f[n];
            double ang = -TWO_PI * (double)(t * n) / (double)SCOPE;
            re += x * cos(ang);
            im += x * sin(ang);
        }
        double d = re * re + im * im;
        hre[t] = re / d;
        him[t] = -im / d;
    }
    __syncthreads();
    if (t < SCOPE) {
        double acc = 0.0;
        for (int k = 0; k < SCOPE; ++k) {
            double ang = TWO_PI * (double)(k * t) / (double)SCOPE;
            acc += hre[k] * cos(ang) - him[k] * sin(ang);
        }
        g[t] = (float)(acc / (double)SCOPE);
    }
}

// ---------------------------------------------------------------------------
// Kernel 2: circulant matmul via MFMA, bf16-at-staging, swizzled LDS.
//
// LDS map (48 KB, 3 blocks/CU):
//   [w*8192 .. w*8192+4096)   Ahi: wave w's 32 rows, [rr][64] bf16, 128 B/row,
//                             each 16B group XOR-swizzled: byte ^= (rr&7)<<4
//   [.. +8192)                Alo: same layout
//   [32768 .. 40960)          Bhi fragments: [(nt*2+kt)*64 + lane][8] bf16
//   [40960 .. 49152)          Blo fragments
// After MFMA, wave w's OUTPUT (32 rows x [64] fp32, 256 B/row, same XOR)
// overwrites its own Ahi+Alo region (8192 B) — wave-local, no extra barrier.
//
// Phase 1 (parallel): waves 0-1 stage A (1 thread/row: 16 ld4u, cvt hi/lo,
// 16 ds_write_b128 swizzled); waves 2-3 build B-fragments from global g.
// One barrier. Phase 2: 8 aligned b128 A-frag reads + 8 B reads + 48 MFMA
// + 32 dword C-writes per wave. One barrier. Phase 3: coalesced store.
//
// Fragment math identical to r19 (passed, absmax 0.03125):
//   OUT = Ahi*Bhi + Ahi*Blo + Alo*Bhi; K,N padded to 64 with zeros.
// ---------------------------------------------------------------------------
__global__ void __launch_bounds__(BT)
circ_conv_kernel(const float* __restrict__ A,
                 const float* __restrict__ G,
                 float* __restrict__ O) {
    __shared__ __align__(16) unsigned char lds[49152];

    const int tid = threadIdx.x;
    const long long row0 = (long long)blockIdx.x * RPB;
    const float* __restrict__ src = A + row0 * SCOPE;
    float* __restrict__ dst       = O + row0 * SCOPE;

    if (tid < 128) {
        // ---- stage one row -> bf16 hi/lo, swizzled padded [64] ----
        const int gr = tid, wq = gr >> 5, rr = gr & 31;
        const float* rp = src + gr * SCOPE;
        float4 v[16];
#pragma unroll
        for (int j = 0; j < 15; ++j) v[j] = ld4u(rp + 4 * j);
        v[15] = ld4u(rp + 59);                 // floats 59..62, no overread
        unsigned char* ab = lds + wq * 8192 + rr * 128;
#pragma unroll
        for (int gk = 0; gk < 8; ++gk) {
            v8bf hv, lv;
#pragma unroll
            for (int e = 0; e < 8; ++e) {
                const int k = gk * 8 + e;
                float x;
                if (k < 60)      x = v[k >> 2][k & 3];
                else if (k < 63) x = v[15][k - 59];
                else             x = 0.0f;     // K pad
                __bf16 hb = (__bf16)x;
                hv[e] = hb;
                lv[e] = (__bf16)(x - (float)hb);
            }
            const int off = (gk * 16) ^ ((rr & 7) << 4);
            *(v8bf*)(ab + off)        = hv;
            *(v8bf*)(ab + 4096 + off) = lv;
        }
    } else {
        // ---- build B fragments from g (global, L2-resident, block-invariant) ----
#pragma unroll
        for (int s = 0; s < 4; ++s) {
            const int cf = (tid - 128) + 128 * s;        // 0..511
            const int nt = cf >> 7, kt = (cf >> 6) & 1, fl = cf & 63;
            v8bf hv, lv;
#pragma unroll
            for (int j = 0; j < 8; ++j) {
                const int k = 8 * (fl >> 4) + j + 32 * kt;
                const int n = 16 * nt + (fl & 15);
                float x = (k < SCOPE && n < SCOPE) ? G[(n - k + SCOPE) % SCOPE] : 0.0f;
                __bf16 hb = (__bf16)x;
                hv[j] = hb;
                lv[j] = (__bf16)(x - (float)hb);
            }
            *(v8bf*)(lds + 32768 + cf * 16) = hv;
            *(v8bf*)(lds + 40960 + cf * 16) = lv;
        }
    }

    __syncthreads();   // A staged, B built

    // ---- compute: wave w owns rows 32w..32w+31 ----
    const int w = tid >> 6, l = tid & 63, c = l & 15, q = l >> 4;  // q in 0..3
    unsigned char* wb = lds + w * 8192;

    v8bf ah[2][2], al[2][2];   // [mt][kt]
#pragma unroll
    for (int mt = 0; mt < 2; ++mt)
#pragma unroll
        for (int kt = 0; kt < 2; ++kt) {
            const int rr = 16 * mt + c, gk = q + 4 * kt;
            const int off = rr * 128 + ((gk * 16) ^ ((rr & 7) << 4));
            ah[mt][kt] = *(const v8bf*)(wb + off);
            al[mt][kt] = *(const v8bf*)(wb + 4096 + off);
        }

#pragma unroll
    for (int nt = 0; nt < 4; ++nt) {
        v8bf bh[2], bl[2];
#pragma unroll
        for (int kt = 0; kt < 2; ++kt) {
            const int bo = ((nt * 2 + kt) * 64 + l) * 16;
            bh[kt] = *(const v8bf*)(lds + 32768 + bo);
            bl[kt] = *(const v8bf*)(lds + 40960 + bo);
        }
#pragma unroll
        for (int mt = 0; mt < 2; ++mt) {
            f32x4 acc = {0.f, 0.f, 0.f, 0.f};
#pragma unroll
            for (int kt = 0; kt < 2; ++kt) {
                acc = __builtin_amdgcn_mfma_f32_16x16x32_bf16(ah[mt][kt], bh[kt], acc, 0, 0, 0);
                acc = __builtin_amdgcn_mfma_f32_16x16x32_bf16(ah[mt][kt], bl[kt], acc, 0, 0, 0);
                acc = __builtin_amdgcn_mfma_f32_16x16x32_bf16(al[mt][kt], bh[kt], acc, 0, 0, 0);
            }
            // C: col = 16nt+c, local row rr = 16mt + 4q + i; overwrite own region
            const int col = 16 * nt + c;
            if (col < SCOPE) {
#pragma unroll
                for (int i = 0; i < 4; ++i) {
                    const int rr = 16 * mt + 4 * q + i;
                    const int off = rr * 256 + ((col * 4) ^ ((rr & 7) << 4));
                    *(float*)(wb + off) = acc[i];
                }
            }
        }
    }

    __syncthreads();   // all outputs in LDS

    // ---- coalesced store: 2 threads/row, swizzle-consistent reads ----
    {
        const int gr = tid >> 1, h = tid & 1, wq = gr >> 5, rr = gr & 31;
        unsigned char* ob = lds + wq * 8192 + rr * 256;
        float* op = dst + gr * SCOPE;
#pragma unroll
        for (int j = 0; j < 8; ++j) {
            const int off = (h * 128 + j * 16) ^ ((rr & 7) << 4);
            float4 vv = *(const float4*)(ob + off);
            if (h == 0)      st4u(op + 4 * j, vv);
            else if (j < 7)  st4u(op + 32 + 4 * j, vv);
            else { op[60] = vv.x; op[61] = vv.y; op[62] = vv.z; }  // skip pad 63
        }
    }
}

// ---------------------------------------------------------------------------
extern "C" void kernel_launch(void* const* d_in, const int* in_sizes, int n_in,
                              void* d_out, int out_size, void* d_ws, size_t ws_size,
                              hipStream_t stream) {
    const float* activations = (const float*)d_in[0];
    const float* filt        = (const float*)d_in[1];
    float* out               = (float*)d_out;
    float* g                 = (float*)d_ws;   // 63 floats of scratch

    hipLaunchKernelGGL(compute_inverse_filter, dim3(1), dim3(64), 0, stream,
                       filt, g);

    const long long total = (long long)in_sizes[0];
    const long long rows  = total / SCOPE;          // 524288
    const int blocks      = (int)(rows / RPB);      // 4096, exact

    hipLaunchKernelGGL(circ_conv_kernel, dim3(blocks), dim3(BT), 0,
                       stream, activations, g, out);
}

// Round 22
// 93.627 us; speedup vs baseline: 2.2432x; 2.2432x over previous
//
#include <hip/hip_runtime.h>
#include <hip/hip_bf16.h>

#define SCOPE 63
#define BT 256
#define RPB 128                     // rows per tile
#define TILE_ELEMS (RPB * SCOPE)    // 8064 floats
#define TPB 4                       // tiles per block

typedef __attribute__((ext_vector_type(8))) __bf16 v8bf;
typedef __attribute__((ext_vector_type(4))) float f32x4;

// ---------------------------------------------------------------------------
// Kernel 1: inverse filter g = IFFT( 1 / FFT(delta - f) ) in fp64. Negligible.
// ---------------------------------------------------------------------------
__global__ void compute_inverse_filter(const float* __restrict__ f,
                                       float* __restrict__ g) {
    __shared__ double hre[SCOPE];
    __shared__ double him[SCOPE];
    const double TWO_PI = 6.283185307179586476925286766559;
    int t = threadIdx.x;
    if (t < SCOPE) {
        double re = 0.0, im = 0.0;
        for (int n = 0; n < SCOPE; ++n) {
            double x = (n == 0 ? 1.0 : 0.0) - (double)f[n];
            double ang = -TWO_PI * (double)(t * n) / (double)SCOPE;
            re += x * cos(ang);
            im += x * sin(ang);
        }
        double d = re * re + im * im;
        hre[t] = re / d;
        him[t] = -im / d;
    }
    __syncthreads();
    if (t < SCOPE) {
        double acc = 0.0;
        for (int k = 0; k < SCOPE; ++k) {
            double ang = TWO_PI * (double)(k * t) / (double)SCOPE;
            acc += hre[k] * cos(ang) - him[k] * sin(ang);
        }
        g[t] = (float)(acc / (double)SCOPE);
    }
}

// ---------------------------------------------------------------------------
// Kernel 2: r19 circulant-MFMA structure (79 us, verified absmax 0.03125),
// pipelined 4 tiles/block with register prefetch (T14 safe variant):
//   - prefetch tile t+1 -> 8 float4 regs (coalesced dwordx4) at top of
//     compute(t); regs -> LDS after the store phase. Single 32 KB tile buffer
//     keeps LDS at 49 KB -> 3 blocks/CU (r16's dbuf at 80 KB halved occupancy).
//   - __syncthreads everywhere: the vmcnt drain at the post-compute barrier is
//     ~free since prefetch loads land during compute. No raw-barrier races.
//   - B fragments built ONCE per block (amortized over 4 tiles).
//   - k=63 overread pad zeroed (NaN-proof: garbage * B[63]=0 stays 0).
// Fragment math identical to r19: OUT = Ahi*Bhi + Ahi*Blo + Alo*Bhi.
// ---------------------------------------------------------------------------
__global__ void __launch_bounds__(BT)
circ_conv_kernel(const float* __restrict__ A,
                 const float* __restrict__ G,
                 float* __restrict__ O) {
    __shared__ __align__(16) float tile[TILE_ELEMS + 16];  // +pad for k-overread
    __shared__ __align__(16) __bf16 Bhi[4096];             // [nt][kt][lane][8]
    __shared__ __align__(16) __bf16 Blo[4096];
    __shared__ float gs[SCOPE];

    const int tid = threadIdx.x;
    const int w   = tid >> 6;        // wave in block
    const int l   = tid & 63;        // lane in wave
    const int c   = l & 15;          // fragment column index
    const int q   = l >> 4;          // fragment k-group / row-group

    const long long t0 = (long long)blockIdx.x * TPB;

    // ---- prologue: prefetch tile 0 into regs (coalesced), gs, zero pad ----
    float4 pf0, pf1, pf2, pf3, pf4, pf5, pf6, pf7;
    {
        const float4* s4 = (const float4*)(A + t0 * (long long)TILE_ELEMS);
        pf0 = s4[0 * 256 + tid]; pf1 = s4[1 * 256 + tid];
        pf2 = s4[2 * 256 + tid]; pf3 = s4[3 * 256 + tid];
        pf4 = s4[4 * 256 + tid]; pf5 = s4[5 * 256 + tid];
        pf6 = s4[6 * 256 + tid];
        pf7 = make_float4(0.f, 0.f, 0.f, 0.f);
        if (tid < 224) pf7 = s4[1792 + tid];
    }
    if (tid < SCOPE) gs[tid] = G[tid];
    if (tid < 16) tile[TILE_ELEMS + tid] = 0.0f;
    __syncthreads();   // gs visible (prefetch also drained)

    // ---- build B fragments once per block ----
    for (int f = tid; f < 4096; f += BT) {
        const int j  = f & 7;
        const int fl = (f >> 3) & 63;
        const int kt = (f >> 9) & 1;
        const int nt = f >> 10;
        const int k  = 8 * (fl >> 4) + j + 32 * kt;
        const int n  = 16 * nt + (fl & 15);
        float v = (k < SCOPE && n < SCOPE) ? gs[(n - k + SCOPE) % SCOPE] : 0.0f;
        __bf16 h = (__bf16)v;
        Bhi[f] = h;
        Blo[f] = (__bf16)(v - (float)h);
    }

    // ---- write tile 0 ----
    float4* w4 = (float4*)tile;
    w4[0 * 256 + tid] = pf0; w4[1 * 256 + tid] = pf1;
    w4[2 * 256 + tid] = pf2; w4[3 * 256 + tid] = pf3;
    w4[4 * 256 + tid] = pf4; w4[5 * 256 + tid] = pf5;
    w4[6 * 256 + tid] = pf6;
    if (tid < 224) w4[1792 + tid] = pf7;
    __syncthreads();   // B + tile 0 ready

    for (int t = 0; t < TPB; ++t) {
        // ---- prefetch tile t+1 into regs (in flight under compute) ----
        if (t + 1 < TPB) {
            const float4* n4 =
                (const float4*)(A + (t0 + t + 1) * (long long)TILE_ELEMS);
            pf0 = n4[0 * 256 + tid]; pf1 = n4[1 * 256 + tid];
            pf2 = n4[2 * 256 + tid]; pf3 = n4[3 * 256 + tid];
            pf4 = n4[4 * 256 + tid]; pf5 = n4[5 * 256 + tid];
            pf6 = n4[6 * 256 + tid];
            if (tid < 224) pf7 = n4[1792 + tid];
        }

        // ---- compute: A frags -> 48 MFMA -> C back into own rows ----
        v8bf ah[2][2], al[2][2];   // [mt][kt]
#pragma unroll
        for (int mt = 0; mt < 2; ++mt)
#pragma unroll
            for (int kt = 0; kt < 2; ++kt) {
                const float* ap = tile + (32 * w + 16 * mt + c) * SCOPE
                                + 8 * q + 32 * kt;
#pragma unroll
                for (int j = 0; j < 8; ++j) {
                    float v = ap[j];             // k=63 overread: pad/next row, *0
                    __bf16 h = (__bf16)v;
                    ah[mt][kt][j] = h;
                    al[mt][kt][j] = (__bf16)(v - (float)h);
                }
            }

#pragma unroll
        for (int nt = 0; nt < 4; ++nt) {
            v8bf bh[2], bl[2];
#pragma unroll
            for (int kt = 0; kt < 2; ++kt) {
                const int base = ((nt * 2 + kt) * 64 + l) * 8;
                bh[kt] = *reinterpret_cast<const v8bf*>(&Bhi[base]);
                bl[kt] = *reinterpret_cast<const v8bf*>(&Blo[base]);
            }
#pragma unroll
            for (int mt = 0; mt < 2; ++mt) {
                f32x4 acc = {0.f, 0.f, 0.f, 0.f};
#pragma unroll
                for (int kt = 0; kt < 2; ++kt) {
                    acc = __builtin_amdgcn_mfma_f32_16x16x32_bf16(ah[mt][kt], bh[kt], acc, 0, 0, 0);
                    acc = __builtin_amdgcn_mfma_f32_16x16x32_bf16(ah[mt][kt], bl[kt], acc, 0, 0, 0);
                    acc = __builtin_amdgcn_mfma_f32_16x16x32_bf16(al[mt][kt], bh[kt], acc, 0, 0, 0);
                }
                const int col = 16 * nt + c;
                if (col < SCOPE) {
                    float* cp = tile + (32 * w + 16 * mt + 4 * q) * SCOPE + col;
#pragma unroll
                    for (int i = 0; i < 4; ++i)
                        cp[i * SCOPE] = acc[i];
                }
            }
        }

        __syncthreads();   // C visible block-wide (prefetch loads landed too)

        // ---- coalesced store of tile t ----
        float4* d4 = (float4*)(O + (t0 + t) * (long long)TILE_ELEMS);
#pragma unroll
        for (int it = 0; it < 7; ++it)
            d4[it * 256 + tid] = w4[it * 256 + tid];
        if (tid < 224)
            d4[1792 + tid] = w4[1792 + tid];
        __syncthreads();   // all LDS reads of tile done -> safe to overwrite

        // ---- stage tile t+1 from regs ----
        if (t + 1 < TPB) {
            w4[0 * 256 + tid] = pf0; w4[1 * 256 + tid] = pf1;
            w4[2 * 256 + tid] = pf2; w4[3 * 256 + tid] = pf3;
            w4[4 * 256 + tid] = pf4; w4[5 * 256 + tid] = pf5;
            w4[6 * 256 + tid] = pf6;
            if (tid < 224) w4[1792 + tid] = pf7;
            __syncthreads();   // tile t+1 ready
        }
    }
}

// ---------------------------------------------------------------------------
extern "C" void kernel_launch(void* const* d_in, const int* in_sizes, int n_in,
                              void* d_out, int out_size, void* d_ws, size_t ws_size,
                              hipStream_t stream) {
    const float* activations = (const float*)d_in[0];
    const float* filt        = (const float*)d_in[1];
    float* out               = (float*)d_out;
    float* g                 = (float*)d_ws;   // 63 floats of scratch

    hipLaunchKernelGGL(compute_inverse_filter, dim3(1), dim3(64), 0, stream,
                       filt, g);

    const long long total = (long long)in_sizes[0];
    const long long rows  = total / SCOPE;                  // 524288
    const int blocks = (int)(rows / (RPB * TPB));           // 1024, exact

    hipLaunchKernelGGL(circ_conv_kernel, dim3(blocks), dim3(BT), 0,
                       stream, activations, g, out);
}

// Round 27
// 91.902 us; speedup vs baseline: 2.2853x; 1.0188x over previous
//
#include <hip/hip_runtime.h>
#include <hip/hip_bf16.h>

#define SCOPE 63
#define BT 256
#define RPB 128                     // rows per block
#define TILE_ELEMS (RPB * SCOPE)    // 8064 floats

typedef __attribute__((ext_vector_type(8))) __bf16 v8bf;
typedef __attribute__((ext_vector_type(4))) float f32x4;

// async global->LDS, 16B per lane; LDS dest is wave-uniform base + lane*16
#define GLL(gp, lp) __builtin_amdgcn_global_load_lds(                         \
    (const __attribute__((address_space(1))) void*)(gp),                      \
    (__attribute__((address_space(3))) void*)(lp), 16, 0, 0)

// ws layout: [0,256) g as float[63]; [256, 8448) Bhi bf16[4096];
//            [8448, 16640) Blo bf16[4096]   (fragment order [nt][kt][lane][8])
#define WS_BHI_OFF 256
#define WS_BLO_OFF 8448

// ---------------------------------------------------------------------------
// Kernel 1 (one-time): inverse filter g = IFFT(1/FFT(delta-f)) in fp64, plus
// the fragment-ordered bf16 hi/lo circulant-B arrays into d_ws.
// ---------------------------------------------------------------------------
__global__ void compute_inverse_filter(const float* __restrict__ f,
                                       float* __restrict__ ws) {
    __shared__ double hre[SCOPE];
    __shared__ double him[SCOPE];
    __shared__ float gsm[SCOPE];
    const double TWO_PI = 6.283185307179586476925286766559;
    int t = threadIdx.x;
    if (t < SCOPE) {
        double re = 0.0, im = 0.0;
        for (int n = 0; n < SCOPE; ++n) {
            double x = (n == 0 ? 1.0 : 0.0) - (double)f[n];
            double ang = -TWO_PI * (double)(t * n) / (double)SCOPE;
            re += x * cos(ang);
            im += x * sin(ang);
        }
        double d = re * re + im * im;
        hre[t] = re / d;
        him[t] = -im / d;
    }
    __syncthreads();
    if (t < SCOPE) {
        double acc = 0.0;
        for (int k = 0; k < SCOPE; ++k) {
            double ang = TWO_PI * (double)(k * t) / (double)SCOPE;
            acc += hre[k] * cos(ang) - him[k] * sin(ang);
        }
        float gv = (float)(acc / (double)SCOPE);
        ws[t] = gv;          // keep g in ws[0..63) (debug/compat)
        gsm[t] = gv;
    }
    __syncthreads();
    // ---- build B fragments in ws (block-invariant, built once ever) ----
    __bf16* Bhi = (__bf16*)((char*)ws + WS_BHI_OFF);
    __bf16* Blo = (__bf16*)((char*)ws + WS_BLO_OFF);
    for (int fidx = t; fidx < 4096; fidx += blockDim.x) {
        const int j  = fidx & 7;
        const int fl = (fidx >> 3) & 63;
        const int kt = (fidx >> 9) & 1;
        const int nt = fidx >> 10;
        const int k  = 8 * (fl >> 4) + j + 32 * kt;
        const int n  = 16 * nt + (fl & 15);
        float v = (k < SCOPE && n < SCOPE) ? gsm[(n - k + SCOPE) % SCOPE] : 0.0f;
        __bf16 h = (__bf16)v;
        Bhi[fidx] = h;
        Blo[fidx] = (__bf16)(v - (float)h);
    }
}

// ---------------------------------------------------------------------------
// Kernel 2: circulant matmul via MFMA (r19 math, verified absmax 0.03125).
//   OUT = Ahi*Bhi + Ahi*Blo + Alo*Bhi; K,N padded to 64 with zeros.
// Changes vs r22: B-fragments live in GLOBAL ws (L2-resident broadcast,
// coalesced lane->16B loads) instead of per-block LDS; no B-build, no gs.
// LDS = A/C tile only: 32.3 KB -> 4 blocks/CU (was 3 at 49 KB).
// Staging via GLL width=16 (r17/r19, coalesced); 2 barriers total.
// ---------------------------------------------------------------------------
__global__ void __launch_bounds__(BT)
circ_conv_kernel(const float* __restrict__ A,
                 const float* __restrict__ WS,
                 float* __restrict__ O) {
    __shared__ __align__(16) float tile[TILE_ELEMS + 16];  // +pad for k-overread

    const int tid = threadIdx.x;
    const int w   = tid >> 6;        // wave in block
    const int l   = tid & 63;        // lane in wave
    const int c   = l & 15;          // fragment column index
    const int q   = l >> 4;          // fragment k-group / row-group

    const long long row0 = (long long)blockIdx.x * RPB;
    const float* __restrict__ src = A + row0 * SCOPE;
    float* __restrict__ dst       = O + row0 * SCOPE;

    // ---- stage 128 rows (2016 float4) via async global->LDS ----
    const float4* src4 = (const float4*)src;
    float4* w4 = (float4*)tile;
#pragma unroll
    for (int it = 0; it < 7; ++it)
        GLL(src4 + it * 256 + tid, w4 + it * 256 + tid);
    if (tid < 224)
        GLL(src4 + 1792 + tid, w4 + 1792 + tid);
    if (tid < 16) tile[TILE_ELEMS + tid] = 0.0f;   // zero k-overread pad

    // ---- B fragments: global, identical across blocks -> L2 broadcast ----
    const v8bf* BH = (const v8bf*)((const char*)WS + WS_BHI_OFF);
    const v8bf* BL = (const v8bf*)((const char*)WS + WS_BLO_OFF);
    v8bf bh[4][2], bl[4][2];
#pragma unroll
    for (int nt = 0; nt < 4; ++nt)
#pragma unroll
        for (int kt = 0; kt < 2; ++kt) {
            bh[nt][kt] = BH[(nt * 2 + kt) * 64 + l];
            bl[nt][kt] = BL[(nt * 2 + kt) * 64 + l];
        }

    __syncthreads();   // tile ready (vmcnt drained)

    // ---- A fragments: rows 32w + 16mt + c, 8 floats at koff = 8q + 32kt ----
    v8bf ah[2][2], al[2][2];   // [mt][kt]
#pragma unroll
    for (int mt = 0; mt < 2; ++mt)
#pragma unroll
        for (int kt = 0; kt < 2; ++kt) {
            const float* ap = tile + (32 * w + 16 * mt + c) * SCOPE
                            + 8 * q + 32 * kt;
#pragma unroll
            for (int j = 0; j < 8; ++j) {
                float v = ap[j];             // k=63 overread: pad/next row, *0
                __bf16 h = (__bf16)v;
                ah[mt][kt][j] = h;
                al[mt][kt][j] = (__bf16)(v - (float)h);
            }
        }

    // ---- 4 N-tiles x 2 M-tiles x (2 kt x 3 passes) MFMA ----
#pragma unroll
    for (int nt = 0; nt < 4; ++nt) {
#pragma unroll
        for (int mt = 0; mt < 2; ++mt) {
            f32x4 acc = {0.f, 0.f, 0.f, 0.f};
#pragma unroll
            for (int kt = 0; kt < 2; ++kt) {
                acc = __builtin_amdgcn_mfma_f32_16x16x32_bf16(ah[mt][kt], bh[nt][kt], acc, 0, 0, 0);
                acc = __builtin_amdgcn_mfma_f32_16x16x32_bf16(ah[mt][kt], bl[nt][kt], acc, 0, 0, 0);
                acc = __builtin_amdgcn_mfma_f32_16x16x32_bf16(al[mt][kt], bh[nt][kt], acc, 0, 0, 0);
            }
            // C: col = 16nt + c, rows 32w + 16mt + 4q + i (own rows)
            const int col = 16 * nt + c;
            if (col < SCOPE) {
                float* cp = tile + (32 * w + 16 * mt + 4 * q) * SCOPE + col;
#pragma unroll
                for (int i = 0; i < 4; ++i)
                    cp[i * SCOPE] = acc[i];
            }
        }
    }

    __syncthreads();   // all outputs in tile

    // ---- coalesced float4 store ----
    float4* dst4 = (float4*)dst;
#pragma unroll
    for (int it = 0; it < 7; ++it)
        dst4[it * 256 + tid] = w4[it * 256 + tid];
    if (tid < 224)
        dst4[1792 + tid] = w4[1792 + tid];
}

// ---------------------------------------------------------------------------
extern "C" void kernel_launch(void* const* d_in, const int* in_sizes, int n_in,
                              void* d_out, int out_size, void* d_ws, size_t ws_size,
                              hipStream_t stream) {
    const float* activations = (const float*)d_in[0];
    const float* filt        = (const float*)d_in[1];
    float* out               = (float*)d_out;
    float* ws                = (float*)d_ws;   // g + B-fragment arrays (~17 KB)

    hipLaunchKernelGGL(compute_inverse_filter, dim3(1), dim3(BT), 0, stream,
                       filt, ws);

    const long long total = (long long)in_sizes[0];
    const long long rows  = total / SCOPE;          // 524288
    const int blocks      = (int)(rows / RPB);      // 4096, exact

    hipLaunchKernelGGL(circ_conv_kernel, dim3(blocks), dim3(BT), 0,
                       stream, activations, ws, out);
}